// Round 3
// baseline (376.583 us; speedup 1.0000x reference)
//
#include <hip/hip_runtime.h>

#define KH 18          // total harmonics
#define NPTS (128*128*128)
#define BB 4           // batch
#define BLK 256
#define TILE (BLK * KH)            // 4608 floats = 18432 B (one array's tile)

// Hybrid of r0+r1: coalesced float4 LDS staging (exact-demand HBM traffic)
// + in-register Chebyshev trig recurrence (no LDS trig tables).
// One 18.4 KB buffer used twice (fa pass: cos, fb pass: sin).
// fb is prefetched into registers before pass A (issue-early / write-late).
// launch_bounds(256,6): <=84 VGPR so the fb prefetch doesn't force spills.
__global__ __launch_bounds__(BLK, 6) void dddm_kernel(
    const float* __restrict__ input_t,
    const float* __restrict__ poly,    // [N,4]
    const float* __restrict__ fa,      // [N,18]
    const float* __restrict__ fb,      // [N,18]
    const int*   __restrict__ stage_p,
    float* __restrict__ out)           // [2,B,N] concat: y_poly then y_fourier
{
    __shared__ float s[TILE];

    const int tid = threadIdx.x;
    const int n0  = blockIdx.x * BLK;
    const int n   = n0 + tid;

    // ---- uniform per-batch seeds ----
    float tb[BB], c1[BB], s1[BB], d[BB];
#pragma unroll
    for (int b = 0; b < BB; ++b) {
        const float t = input_t[b];
        tb[b] = t;
        float sn, cs;
        sincosf(6.283185307179586f * t, &sn, &cs);
        c1[b] = cs; s1[b] = sn; d[b] = 2.0f * cs;
    }

    // ---- coalesced staging: fa tile -> LDS; fb tile -> registers (prefetch) ----
    // tile = 1152 float4; 256 threads x 4 + first 128 threads x 1
    const float4* fa4 = reinterpret_cast<const float4*>(fa + (size_t)n0 * KH);
    const float4* fb4 = reinterpret_cast<const float4*>(fb + (size_t)n0 * KH);
    float4* s4 = reinterpret_cast<float4*>(s);

    float4 va[4], vb[4];
    float4 va5 = make_float4(0.f, 0.f, 0.f, 0.f);
    float4 vb5 = make_float4(0.f, 0.f, 0.f, 0.f);
#pragma unroll
    for (int j = 0; j < 4; ++j) va[j] = fa4[j * BLK + tid];
    if (tid < 128) va5 = fa4[4 * BLK + tid];
#pragma unroll
    for (int j = 0; j < 4; ++j) vb[j] = fb4[j * BLK + tid];   // issue early
    if (tid < 128) vb5 = fb4[4 * BLK + tid];

#pragma unroll
    for (int j = 0; j < 4; ++j) s4[j * BLK + tid] = va[j];
    if (tid < 128) s4[4 * BLK + tid] = va5;

    // stage gating (block-uniform)
    const int ms = *stage_p;
    const int cs_ = (ms >= 0) ? (ms < 3 ? ms : 3) : 3;
    const int kmax = (cs_ >= 3) ? 18 : (cs_ == 2 ? 9 : (cs_ == 1 ? 3 : 0));

    __syncthreads();

    // ---- polynomial: 16B-aligned row -> float4 + Horner ----
    const float4 c4 = reinterpret_cast<const float4*>(poly)[n];
    float yp[BB], yf[BB];
#pragma unroll
    for (int b = 0; b < BB; ++b) {
        const float t = tb[b];
        yp[b] = ((c4.w * t + c4.z) * t + c4.y) * t + c4.x;
        yf[b] = 0.0f;
    }

    // ---- pass A: yf += sum_k a_k * cos(k*theta_b), cos-only recurrence ----
    {
        const float2* ar = reinterpret_cast<const float2*>(s + tid * KH);
        if (kmax == KH) {
            float cc[BB], cp[BB];
#pragma unroll
            for (int b = 0; b < BB; ++b) { cc[b] = c1[b]; cp[b] = 1.0f; }
#pragma unroll
            for (int j = 0; j < 9; ++j) {
                const float2 a2 = ar[j];
#pragma unroll
                for (int u = 0; u < 2; ++u) {
                    const float ak = u ? a2.y : a2.x;
#pragma unroll
                    for (int b = 0; b < BB; ++b) {
                        yf[b] = __builtin_fmaf(ak, cc[b], yf[b]);
                        const float cn = __builtin_fmaf(d[b], cc[b], -cp[b]);
                        cp[b] = cc[b]; cc[b] = cn;
                    }
                }
            }
        } else if (kmax > 0) {
            float cc[BB], cp[BB];
#pragma unroll
            for (int b = 0; b < BB; ++b) { cc[b] = c1[b]; cp[b] = 1.0f; }
            for (int k = 0; k < kmax; ++k) {
                const float ak = s[tid * KH + k];
#pragma unroll
                for (int b = 0; b < BB; ++b) {
                    yf[b] = __builtin_fmaf(ak, cc[b], yf[b]);
                    const float cn = __builtin_fmaf(d[b], cc[b], -cp[b]);
                    cp[b] = cc[b]; cc[b] = cn;
                }
            }
        }
    }

    __syncthreads();   // all reads of fa tile done

    // ---- write-late: fb tile into the same buffer ----
#pragma unroll
    for (int j = 0; j < 4; ++j) s4[j * BLK + tid] = vb[j];
    if (tid < 128) s4[4 * BLK + tid] = vb5;

    __syncthreads();

    // ---- pass B: yf += sum_k b_k * sin(k*theta_b), sin-only recurrence ----
    {
        const float2* br = reinterpret_cast<const float2*>(s + tid * KH);
        if (kmax == KH) {
            float ss[BB], sp[BB];
#pragma unroll
            for (int b = 0; b < BB; ++b) { ss[b] = s1[b]; sp[b] = 0.0f; }
#pragma unroll
            for (int j = 0; j < 9; ++j) {
                const float2 b2 = br[j];
#pragma unroll
                for (int u = 0; u < 2; ++u) {
                    const float bk = u ? b2.y : b2.x;
#pragma unroll
                    for (int b = 0; b < BB; ++b) {
                        yf[b] = __builtin_fmaf(bk, ss[b], yf[b]);
                        const float sn = __builtin_fmaf(d[b], ss[b], -sp[b]);
                        sp[b] = ss[b]; ss[b] = sn;
                    }
                }
            }
        } else if (kmax > 0) {
            float ss[BB], sp[BB];
#pragma unroll
            for (int b = 0; b < BB; ++b) { ss[b] = s1[b]; sp[b] = 0.0f; }
            for (int k = 0; k < kmax; ++k) {
                const float bk = s[tid * KH + k];
#pragma unroll
                for (int b = 0; b < BB; ++b) {
                    yf[b] = __builtin_fmaf(bk, ss[b], yf[b]);
                    const float sn = __builtin_fmaf(d[b], ss[b], -sp[b]);
                    sp[b] = ss[b]; ss[b] = sn;
                }
            }
        }
    }

    // ---- store: coalesced dword per (output, b) plane ----
#pragma unroll
    for (int b = 0; b < BB; ++b) {
        out[(size_t)b * NPTS + n]        = yp[b];
        out[(size_t)(BB + b) * NPTS + n] = yf[b];
    }
}

extern "C" void kernel_launch(void* const* d_in, const int* in_sizes, int n_in,
                              void* d_out, int out_size, void* d_ws, size_t ws_size,
                              hipStream_t stream) {
    const float* input_t = (const float*)d_in[0];
    const float* poly    = (const float*)d_in[1];
    const float* fa      = (const float*)d_in[2];
    const float* fb      = (const float*)d_in[3];
    const int*   stage   = (const int*)d_in[4];
    float* out = (float*)d_out;

    dddm_kernel<<<NPTS / BLK, BLK, 0, stream>>>(input_t, poly, fa, fb, stage, out);
}

// Round 4
// 349.160 us; speedup vs baseline: 1.0785x; 1.0785x over previous
//
#include <hip/hip_runtime.h>

#define KH 18          // total harmonics
#define NPTS (128*128*128)
#define BB 4           // batch
#define BLK 256
#define TILE (BLK * KH)            // 4608 floats = 18432 B per array tile

// Round-0 staging structure (proven: exact HBM traffic, zero spills) with the
// trig tables replaced by an in-register Chebyshev recurrence seeded from 12 B
// of LDS. No register value lives across a barrier; launch_bounds(256,4) keeps
// the allocator far from its budget (128 VGPR) so nothing spills to scratch.
__global__ __launch_bounds__(BLK, 4) void dddm_kernel(
    const float* __restrict__ input_t,
    const float* __restrict__ poly,    // [N,4]
    const float* __restrict__ fa,      // [N,18]
    const float* __restrict__ fb,      // [N,18]
    const int*   __restrict__ stage_p,
    float* __restrict__ out)           // [2,B,N] concat: y_poly then y_fourier
{
    __shared__ float s[2 * TILE];      // [0,4608): fa tile, [4608,9216): fb tile
    __shared__ float seedT[BB], seedC[BB], seedS[BB];

    const int tid = threadIdx.x;
    const int n0  = blockIdx.x * BLK;
    const int n   = n0 + tid;

    // ---- per-batch seeds: 4 threads, broadcast via 12 floats of LDS ----
    if (tid < BB) {
        const float t = input_t[tid];
        float sn, cs;
        sincosf(6.283185307179586f * t, &sn, &cs);
        seedT[tid] = t; seedC[tid] = cs; seedS[tid] = sn;
    }

    // ---- coalesced staging: both tiles, float4, 9 per thread (r0 verbatim) ----
    const float4* fa4 = reinterpret_cast<const float4*>(fa + (size_t)n0 * KH);
    const float4* fb4 = reinterpret_cast<const float4*>(fb + (size_t)n0 * KH);
    float4* s4 = reinterpret_cast<float4*>(s);

    float4 v[9];
#pragma unroll
    for (int j = 0; j < 9; ++j) {
        const int idx = j * BLK + tid;              // 0..2303
        v[j] = (idx < TILE / 4) ? fa4[idx] : fb4[idx - TILE / 4];
    }
#pragma unroll
    for (int j = 0; j < 9; ++j) {
        const int idx = j * BLK + tid;
        s4[idx] = v[j];                             // linear -> contiguous
    }

    // stage gating (wave-uniform scalar)
    const int ms = *stage_p;
    const int cs_ = (ms >= 0) ? (ms < 3 ? ms : 3) : 3;
    const int kmax = (cs_ >= 3) ? 18 : (cs_ == 2 ? 9 : (cs_ == 1 ? 3 : 0));

    __syncthreads();

    // ---- polynomial: 16B-aligned row -> float4 + Horner ----
    const float4 c4 = reinterpret_cast<const float4*>(poly)[n];
    float d[BB], cc[BB], ss[BB], cp[BB], sp[BB], yp[BB], yf[BB];
#pragma unroll
    for (int b = 0; b < BB; ++b) {
        const float t  = seedT[b];                  // LDS broadcast (free)
        const float c1 = seedC[b];
        const float s1 = seedS[b];
        yp[b] = ((c4.w * t + c4.z) * t + c4.y) * t + c4.x;
        cc[b] = c1; ss[b] = s1;                     // k = 1
        cp[b] = 1.0f; sp[b] = 0.0f;                 // k = 0
        d[b]  = 2.0f * c1;
        yf[b] = 0.0f;
    }

    // ---- fourier: fused cos+sin Chebyshev recurrence, LDS float2 reads ----
    const float2* ar = reinterpret_cast<const float2*>(s + tid * KH);
    const float2* br = reinterpret_cast<const float2*>(s + TILE + tid * KH);

    if (kmax == KH) {
#pragma unroll
        for (int j = 0; j < 9; ++j) {
            const float2 a2 = ar[j];
            const float2 b2 = br[j];
#pragma unroll
            for (int u = 0; u < 2; ++u) {
                const float ak = u ? a2.y : a2.x;
                const float bk = u ? b2.y : b2.x;
#pragma unroll
                for (int b = 0; b < BB; ++b) {
                    yf[b] = __builtin_fmaf(ak, cc[b], yf[b]);
                    yf[b] = __builtin_fmaf(bk, ss[b], yf[b]);
                    const float cn = __builtin_fmaf(d[b], cc[b], -cp[b]);
                    const float sn = __builtin_fmaf(d[b], ss[b], -sp[b]);
                    cp[b] = cc[b]; cc[b] = cn;
                    sp[b] = ss[b]; ss[b] = sn;
                }
            }
        }
    } else if (kmax > 0) {
        for (int k = 0; k < kmax; ++k) {
            const float ak = s[tid * KH + k];
            const float bk = s[TILE + tid * KH + k];
#pragma unroll
            for (int b = 0; b < BB; ++b) {
                yf[b] = __builtin_fmaf(ak, cc[b], yf[b]);
                yf[b] = __builtin_fmaf(bk, ss[b], yf[b]);
                const float cn = __builtin_fmaf(d[b], cc[b], -cp[b]);
                const float sn = __builtin_fmaf(d[b], ss[b], -sp[b]);
                cp[b] = cc[b]; cc[b] = cn;
                sp[b] = ss[b]; ss[b] = sn;
            }
        }
    }

    // ---- store: coalesced dword per (output, b) plane ----
#pragma unroll
    for (int b = 0; b < BB; ++b) {
        out[(size_t)b * NPTS + n]        = yp[b];
        out[(size_t)(BB + b) * NPTS + n] = yf[b];
    }
}

extern "C" void kernel_launch(void* const* d_in, const int* in_sizes, int n_in,
                              void* d_out, int out_size, void* d_ws, size_t ws_size,
                              hipStream_t stream) {
    const float* input_t = (const float*)d_in[0];
    const float* poly    = (const float*)d_in[1];
    const float* fa      = (const float*)d_in[2];
    const float* fb      = (const float*)d_in[3];
    const int*   stage   = (const int*)d_in[4];
    float* out = (float*)d_out;

    dddm_kernel<<<NPTS / BLK, BLK, 0, stream>>>(input_t, poly, fa, fb, stage, out);
}